// Round 2
// baseline (90.894 us; speedup 1.0000x reference)
//
#include <hip/hip_runtime.h>

// GAT-style graph conv: B=2, C=128, N=10000, K=16, fp32 in/out.
//   k1 (gemm, MFMA bf16): wht[b][n][c] = sum_c' W[c][c']*x[b][c'][n] (bf16 packed)
//               si[b][n] = a[0:C].wh[n], sj[b][n] = a[C:2C].wh[n]  (fp32, from acc)
//   k2 (gather): e = leaky(si[idx_i]+sj[idx_j]); A = softmax_k(e)
//               out[b][c][n] = sum_k A[n,k] * wht[b][idx_j[n,k]][c]
// Gather is XCD-pinned: batch = (blockIdx%8)>>2 so each XCD's L2 (4 MiB) only
// caches its batch's 2.56 MB of wht -> random row-gathers become L2 hits.
// R1 changes vs 87us baseline: TNG 32->64 (halves per-block W bf16-conversion
// VALU), TNA 16->32 (halves gather block count / barriers-per-node), softmax
// moved into registers via 16-lane shfl_xor groups (Phase B + 1 barrier gone).

#define BB 2
#define CC 128
#define NN 10000
#define KK 16
#define TNG 64    // nodes per gemm block
#define TNA 32    // nodes per gather block
#define LSTR 136  // xs row stride in ushorts (272 B = 17*16 -> b128-aligned rows)

typedef unsigned int uint32;
typedef __attribute__((ext_vector_type(8))) short short8;   // bf16 A/B frag
typedef __attribute__((ext_vector_type(4))) float floatx4;  // f32 C/D frag

__device__ __forceinline__ uint32 bf16pair(float lo, float hi) {
  // round-to-nearest-even bf16, packed (lo low 16, hi high 16)
  uint32 ulo = __float_as_uint(lo);
  uint32 uhi = __float_as_uint(hi);
  ulo += 0x7fffu + ((ulo >> 16) & 1u);
  uhi += 0x7fffu + ((uhi >> 16) & 1u);
  return (ulo >> 16) | (uhi & 0xffff0000u);
}

// ---------------- GEMM via MFMA 16x16x32 bf16, register-resident W frags ----
// Block: 256 thr (4 waves). Wave w: channels w*32..+31 x 64 nodes.
__global__ __launch_bounds__(256) void gat_gemm(
    const float* __restrict__ x,    // [B,C,N]
    const float* __restrict__ W,    // [C,C] row-major W[o][c]
    const float* __restrict__ a,    // [2C]
    uint32* __restrict__ wht,       // [B,N,C/2] bf16 pairs
    float* __restrict__ si,         // [B,N]
    float* __restrict__ sj) {       // [B,N]
  __shared__ unsigned short xs[TNG * LSTR];   // 17408 B, node-major bf16 x tile
  __shared__ float red[2][4][4][16];          // 2 KB si/sj partials

  const int b    = blockIdx.y;
  const int n0   = blockIdx.x * TNG;
  const int t    = threadIdx.x;
  const int w    = t >> 6;       // wave -> channel group w*32
  const int lane = t & 63;
  const int col  = lane & 15;    // MFMA col (node) / A row (channel)
  const int q    = lane >> 4;    // quad -> k offset q*8

  // --- Stage x tile, transpose to node-major bf16 (coalesced 256B row reads) ---
  {
    const float* xb = x + (size_t)b * CC * NN;
    uint32* xd = (uint32*)xs;
#pragma unroll
    for (int i = 0; i < 16; ++i) {
      int e = t + i * 256;
      int n = e & 63, cp = e >> 6;     // cp = channel pair 0..63
      int c = cp * 2, gn = n0 + n;
      float v0 = 0.f, v1 = 0.f;
      if (gn < NN) { v0 = xb[c * NN + gn]; v1 = xb[(c + 1) * NN + gn]; }
      xd[n * 68 + cp] = bf16pair(v0, v1);
    }
  }

  // --- A-fragments straight from global fp32 W -> bf16 registers (no LDS) ---
  short8 af[2][4];
#pragma unroll
  for (int ci = 0; ci < 2; ++ci) {
    const float* wr = W + (w * 32 + ci * 16 + col) * CC;
#pragma unroll
    for (int s = 0; s < 4; ++s) {
      float4 f0 = *(const float4*)(wr + s * 32 + q * 8);
      float4 f1 = *(const float4*)(wr + s * 32 + q * 8 + 4);
      union { uint32 u[4]; short8 v; } cv;
      cv.u[0] = bf16pair(f0.x, f0.y);
      cv.u[1] = bf16pair(f0.z, f0.w);
      cv.u[2] = bf16pair(f1.x, f1.y);
      cv.u[3] = bf16pair(f1.z, f1.w);
      af[ci][s] = cv.v;
    }
  }
  __syncthreads();

  floatx4 acc[2][4];
#pragma unroll
  for (int ci = 0; ci < 2; ++ci)
#pragma unroll
    for (int nj = 0; nj < 4; ++nj) acc[ci][nj] = (floatx4){0.f, 0.f, 0.f, 0.f};

#pragma unroll
  for (int s = 0; s < 4; ++s) {
    short8 bf[4];
#pragma unroll
    for (int nj = 0; nj < 4; ++nj)
      bf[nj] = *(const short8*)(xs + (nj * 16 + col) * LSTR + s * 32 + q * 8);
#pragma unroll
    for (int ci = 0; ci < 2; ++ci)
#pragma unroll
      for (int nj = 0; nj < 4; ++nj)
        acc[ci][nj] = __builtin_amdgcn_mfma_f32_16x16x32_bf16(af[ci][s], bf[nj], acc[ci][nj], 0, 0, 0);
  }

  // --- Epilogue: channel = w*32+ci*16+q*4+r, node = n0+nj*16+col ---
  float ar[2][4], aj4[2][4];
#pragma unroll
  for (int ci = 0; ci < 2; ++ci)
#pragma unroll
    for (int r = 0; r < 4; ++r) {
      int ch = w * 32 + ci * 16 + q * 4 + r;
      ar[ci][r]  = a[ch];
      aj4[ci][r] = a[CC + ch];
    }

#pragma unroll
  for (int nj = 0; nj < 4; ++nj) {
    int node = n0 + nj * 16 + col;
    float psi = 0.f, psj = 0.f;
#pragma unroll
    for (int ci = 0; ci < 2; ++ci) {
#pragma unroll
      for (int r = 0; r < 4; ++r) {
        psi = fmaf(ar[ci][r], acc[ci][nj][r], psi);
        psj = fmaf(aj4[ci][r], acc[ci][nj][r], psj);
      }
      if (node < NN) {
        uint2 pk;
        pk.x = bf16pair(acc[ci][nj][0], acc[ci][nj][1]);
        pk.y = bf16pair(acc[ci][nj][2], acc[ci][nj][3]);
        uint2* dst = (uint2*)(wht + ((size_t)(b * NN + node)) * (CC / 2) + w * 16 + ci * 8 + q * 2);
        *dst = pk;
      }
    }
    psi += __shfl_down(psi, 32);
    psi += __shfl_down(psi, 16);
    psj += __shfl_down(psj, 32);
    psj += __shfl_down(psj, 16);
    if (q == 0) { red[0][w][nj][col] = psi; red[1][w][nj][col] = psj; }
  }
  __syncthreads();

  if (t < TNG) {
    int gn = n0 + t;
    if (gn < NN) {
      int nj = t >> 4, cl = t & 15;
      float s1 = 0.f, s2 = 0.f;
#pragma unroll
      for (int ww = 0; ww < 4; ++ww) { s1 += red[0][ww][nj][cl]; s2 += red[1][ww][nj][cl]; }
      si[b * NN + gn] = s1;
      sj[b * NN + gn] = s2;
    }
  }
}

// ---------------- Gather: XCD-pinned, bf16 rows, 32 gathers in flight -------
__global__ __launch_bounds__(256) void gat_gather(
    const int* __restrict__ ei,      // [2,B,N,K]
    const uint32* __restrict__ wht,  // [B,N,C/2] bf16 pairs
    const float* __restrict__ si,    // [B,N]
    const float* __restrict__ sj,    // [B,N]
    float* __restrict__ out) {       // [B,C,N]
  __shared__ float Am[TNA][KK];        // 2 KB (softmax'd attention weights)
  __shared__ int   jd[TNA][KK];        // 2 KB
  __shared__ float outT[CC][TNA + 1];  // 16.9 KB

  // XCD pinning: xcd = bk%8; XCDs 0-3 -> batch 0, 4-7 -> batch 1.
  const int bk   = blockIdx.x;
  const int xcd  = bk & 7;
  const int b    = xcd >> 2;
  const int slot = (bk >> 3) * 4 + (xcd & 3);
  if (slot >= (NN + TNA - 1) / TNA) return;   // uniform early-out (313 slots/batch)
  const int n0 = slot * TNA;
  const int t  = threadIdx.x;

  const int* eij = ei + b * NN * KK;          // edge_index[0][b] -> j (source)
  const int* eii = ei + (BB + b) * NN * KK;   // edge_index[1][b] -> i (dest)
  const float* sib = si + b * NN;
  const float* sjb = sj + b * NN;

  // Phase A: two edges per thread; softmax over K=16 done in-register via
  // 16-lane-group shfl_xor reductions (node nn's 16 edges are lane-contiguous).
#pragma unroll
  for (int r = 0; r < 2; ++r) {
    int e = t + r * 256;
    int nn = e >> 4, k = e & 15, gn = n0 + nn;
    int jj = 0, ii = 0;
    if (gn < NN) { jj = eij[gn * KK + k]; ii = eii[gn * KK + k]; }
    float v = sib[ii] + sjb[jj];
    float el = (v > 0.f) ? v : 0.2f * v;   // leaky_relu(0.2)
    float mx = el;
#pragma unroll
    for (int d = 1; d < KK; d <<= 1) mx = fmaxf(mx, __shfl_xor(mx, d));
    float ex = __expf(el - mx);
    float s = ex;
#pragma unroll
    for (int d = 1; d < KK; d <<= 1) s += __shfl_xor(s, d);
    Am[nn][k] = ex / s;
    jd[nn][k] = jj;
  }
  __syncthreads();

  // Phase C: wave = one node row (64 lanes x 1 dword = 256 B); two nodes
  // batched -> 32 independent gathers in flight (all L2-local to this XCD).
  const int cp = t & 63;
  const int nw = t >> 6;
  const uint32* whtb = wht + (size_t)b * NN * (CC / 2);
#pragma unroll
  for (int pr = 0; pr < 4; ++pr) {
    int na = nw * 8 + pr * 2;      // this wave's nodes na, na+1
    int idx[2][KK]; float wk[2][KK];
#pragma unroll
    for (int p = 0; p < 2; ++p) {
      int nn = na + p;
      const uint4*  jp = (const uint4*)&jd[nn][0];   // broadcast b128 reads
      const float4* ap = (const float4*)&Am[nn][0];
#pragma unroll
      for (int g = 0; g < 4; ++g) {
        uint4  jv = jp[g];
        float4 av = ap[g];
        idx[p][4 * g + 0] = jv.x; idx[p][4 * g + 1] = jv.y;
        idx[p][4 * g + 2] = jv.z; idx[p][4 * g + 3] = jv.w;
        wk[p][4 * g + 0] = av.x;  wk[p][4 * g + 1] = av.y;
        wk[p][4 * g + 2] = av.z;  wk[p][4 * g + 3] = av.w;
      }
    }
    uint32 v[2][KK];
#pragma unroll
    for (int p = 0; p < 2; ++p)
#pragma unroll
      for (int k = 0; k < KK; ++k)
        v[p][k] = whtb[(size_t)idx[p][k] * (CC / 2) + cp];
#pragma unroll
    for (int p = 0; p < 2; ++p) {
      int nn = na + p;
      float ax = 0.f, ay = 0.f;
#pragma unroll
      for (int k = 0; k < KK; ++k) {
        ax = fmaf(wk[p][k], __uint_as_float(v[p][k] << 16), ax);
        ay = fmaf(wk[p][k], __uint_as_float(v[p][k] & 0xffff0000u), ay);
      }
      outT[2 * cp][nn]     = ax;
      outT[2 * cp + 1][nn] = ay;
    }
  }
  __syncthreads();

  // Phase D: coalesced channel-major store (128 B segments per half-wave).
  float* outb = out + (size_t)b * CC * NN;
#pragma unroll
  for (int i = 0; i < (CC * TNA) / 256; ++i) {   // 16 iters
    int e = t + i * 256;
    int c = e >> 5, nn = e & 31;
    int gn = n0 + nn;
    if (gn < NN) outb[c * NN + gn] = outT[c][nn];
  }
}

extern "C" void kernel_launch(void* const* d_in, const int* in_sizes, int n_in,
                              void* d_out, int out_size, void* d_ws, size_t ws_size,
                              hipStream_t stream) {
  const float* x  = (const float*)d_in[0];   // [B,C,N,1]
  const int*   ei = (const int*)d_in[1];     // [2,B,N,K]
  const float* W  = (const float*)d_in[2];   // [C,C]
  const float* a  = (const float*)d_in[3];   // [2C]
  float* out = (float*)d_out;                // [B,C,N,1]

  uint32* wht = (uint32*)d_ws;               // [B*N*C/2] bf16 pairs (5.12 MB)
  float*  si  = (float*)(wht + (size_t)BB * NN * (CC / 2));
  float*  sj  = si + BB * NN;

  dim3 g1((NN + TNG - 1) / TNG, BB);   // 157 x 2, 256 threads
  gat_gemm<<<g1, 256, 0, stream>>>(x, W, a, wht, si, sj);
  // 79 groups * 8 XCD-slots = 632 blocks -> 316 slots/batch (313 used)
  gat_gather<<<dim3(79 * 8), 256, 0, stream>>>(ei, wht, si, sj, out);
}

// Round 3
// 86.877 us; speedup vs baseline: 1.0462x; 1.0462x over previous
//
#include <hip/hip_runtime.h>

// GAT-style graph conv: B=2, C=128, N=10000, K=16, fp32 in/out.
//   k1 (gemm, MFMA bf16): wht[b][n][c] = sum_c' W[c][c']*x[b][c'][n] (bf16 packed)
//               si[b][n] = a[0:C].wh[n], sj[b][n] = a[C:2C].wh[n]  (fp32, from acc)
//   k2 (gather): e = leaky(si[idx_i]+sj[idx_j]); A = softmax_k(e)
//               out[b][c][n] = sum_k A[n,k] * wht[b][idx_j[n,k]][c]
// Gather is XCD-pinned: batch = (blockIdx%8)>>2 so each XCD's L2 (4 MiB) only
// caches its batch's 2.56 MB of wht -> random row-gathers become L2 hits.
// R3: revert R2's TNG64/TNA32 (halved block-level MLP -> +4.3us). Keep the
// baseline parallelism (626 gemm blocks, 1256 gather blocks) and add only:
//   - in-register softmax via 16-lane shfl_xor (kills Phase B + 1 barrier)
//   - u32 gather offsets (saddr-form loads, no per-lane 64-bit address adds)

#define BB 2
#define CC 128
#define NN 10000
#define KK 16
#define TNG 32    // nodes per gemm block
#define TNA 16    // nodes per gather block
#define LSTR 136  // xs row stride in ushorts (272 B = 17*16 -> b128-aligned rows)

typedef unsigned int uint32;
typedef __attribute__((ext_vector_type(8))) short short8;   // bf16 A/B frag
typedef __attribute__((ext_vector_type(4))) float floatx4;  // f32 C/D frag

__device__ __forceinline__ uint32 bf16pair(float lo, float hi) {
  // round-to-nearest-even bf16, packed (lo low 16, hi high 16)
  uint32 ulo = __float_as_uint(lo);
  uint32 uhi = __float_as_uint(hi);
  ulo += 0x7fffu + ((ulo >> 16) & 1u);
  uhi += 0x7fffu + ((uhi >> 16) & 1u);
  return (ulo >> 16) | (uhi & 0xffff0000u);
}

// ---------------- GEMM via MFMA 16x16x32 bf16, register-resident W frags ----
// Block: 256 thr (4 waves). Wave w: channels w*32..+31 x 32 nodes.
__global__ __launch_bounds__(256) void gat_gemm(
    const float* __restrict__ x,    // [B,C,N]
    const float* __restrict__ W,    // [C,C] row-major W[o][c]
    const float* __restrict__ a,    // [2C]
    uint32* __restrict__ wht,       // [B,N,C/2] bf16 pairs
    float* __restrict__ si,         // [B,N]
    float* __restrict__ sj) {       // [B,N]
  __shared__ unsigned short xs[TNG * LSTR];   // 8704 B, node-major bf16 x tile
  __shared__ float red[2][4][2][16];          // 1 KB si/sj partials

  const int b    = blockIdx.y;
  const int n0   = blockIdx.x * TNG;
  const int t    = threadIdx.x;
  const int w    = t >> 6;       // wave -> channel group w*32
  const int lane = t & 63;
  const int col  = lane & 15;    // MFMA col (node) / A row (channel)
  const int q    = lane >> 4;    // quad -> k offset q*8

  // --- Stage x tile, transpose to node-major bf16 (coalesced 128B row reads) ---
  {
    const float* xb = x + (size_t)b * CC * NN;
    uint32* xd = (uint32*)xs;
#pragma unroll
    for (int i = 0; i < 8; ++i) {
      int e = t + i * 256;
      int n = e & 31, cp = e >> 5;     // cp = channel pair 0..63
      int c = cp * 2, gn = n0 + n;
      float v0 = 0.f, v1 = 0.f;
      if (gn < NN) { v0 = xb[c * NN + gn]; v1 = xb[(c + 1) * NN + gn]; }
      xd[n * 68 + cp] = bf16pair(v0, v1);
    }
  }

  // --- A-fragments straight from global fp32 W -> bf16 registers (no LDS) ---
  short8 af[2][4];
#pragma unroll
  for (int ci = 0; ci < 2; ++ci) {
    const float* wr = W + (w * 32 + ci * 16 + col) * CC;
#pragma unroll
    for (int s = 0; s < 4; ++s) {
      float4 f0 = *(const float4*)(wr + s * 32 + q * 8);
      float4 f1 = *(const float4*)(wr + s * 32 + q * 8 + 4);
      union { uint32 u[4]; short8 v; } cv;
      cv.u[0] = bf16pair(f0.x, f0.y);
      cv.u[1] = bf16pair(f0.z, f0.w);
      cv.u[2] = bf16pair(f1.x, f1.y);
      cv.u[3] = bf16pair(f1.z, f1.w);
      af[ci][s] = cv.v;
    }
  }
  __syncthreads();

  floatx4 acc[2][2];
#pragma unroll
  for (int ci = 0; ci < 2; ++ci)
#pragma unroll
    for (int nj = 0; nj < 2; ++nj) acc[ci][nj] = (floatx4){0.f, 0.f, 0.f, 0.f};

#pragma unroll
  for (int s = 0; s < 4; ++s) {
    short8 bf[2];
#pragma unroll
    for (int nj = 0; nj < 2; ++nj)
      bf[nj] = *(const short8*)(xs + (nj * 16 + col) * LSTR + s * 32 + q * 8);
#pragma unroll
    for (int ci = 0; ci < 2; ++ci)
#pragma unroll
      for (int nj = 0; nj < 2; ++nj)
        acc[ci][nj] = __builtin_amdgcn_mfma_f32_16x16x32_bf16(af[ci][s], bf[nj], acc[ci][nj], 0, 0, 0);
  }

  // --- Epilogue: channel = w*32+ci*16+q*4+r, node = n0+nj*16+col ---
  float ar[2][4], aj4[2][4];
#pragma unroll
  for (int ci = 0; ci < 2; ++ci)
#pragma unroll
    for (int r = 0; r < 4; ++r) {
      int ch = w * 32 + ci * 16 + q * 4 + r;
      ar[ci][r]  = a[ch];
      aj4[ci][r] = a[CC + ch];
    }

#pragma unroll
  for (int nj = 0; nj < 2; ++nj) {
    int node = n0 + nj * 16 + col;
    float psi = 0.f, psj = 0.f;
#pragma unroll
    for (int ci = 0; ci < 2; ++ci) {
#pragma unroll
      for (int r = 0; r < 4; ++r) {
        psi = fmaf(ar[ci][r], acc[ci][nj][r], psi);
        psj = fmaf(aj4[ci][r], acc[ci][nj][r], psj);
      }
      if (node < NN) {
        uint2 pk;
        pk.x = bf16pair(acc[ci][nj][0], acc[ci][nj][1]);
        pk.y = bf16pair(acc[ci][nj][2], acc[ci][nj][3]);
        uint2* dst = (uint2*)(wht + ((size_t)(b * NN + node)) * (CC / 2) + w * 16 + ci * 8 + q * 2);
        *dst = pk;
      }
    }
    psi += __shfl_down(psi, 32);
    psi += __shfl_down(psi, 16);
    psj += __shfl_down(psj, 32);
    psj += __shfl_down(psj, 16);
    if (q == 0) { red[0][w][nj][col] = psi; red[1][w][nj][col] = psj; }
  }
  __syncthreads();

  if (t < TNG) {
    int gn = n0 + t;
    if (gn < NN) {
      int nj = t >> 4, cl = t & 15;
      float s1 = 0.f, s2 = 0.f;
#pragma unroll
      for (int ww = 0; ww < 4; ++ww) { s1 += red[0][ww][nj][cl]; s2 += red[1][ww][nj][cl]; }
      si[b * NN + gn] = s1;
      sj[b * NN + gn] = s2;
    }
  }
}

// ---------------- Gather: XCD-pinned, bf16 rows, 32 gathers in flight -------
__global__ __launch_bounds__(256) void gat_gather(
    const int* __restrict__ ei,      // [2,B,N,K]
    const uint32* __restrict__ wht,  // [B,N,C/2] bf16 pairs
    const float* __restrict__ si,    // [B,N]
    const float* __restrict__ sj,    // [B,N]
    float* __restrict__ out) {       // [B,C,N]
  __shared__ float Am[TNA][KK];        // 1 KB (softmax'd attention weights)
  __shared__ int   jd[TNA][KK];        // 1 KB
  __shared__ float outT[CC][TNA + 1];  // 8.5 KB

  // XCD pinning: xcd = bk%8; XCDs 0-3 -> batch 0, 4-7 -> batch 1.
  const int bk   = blockIdx.x;
  const int xcd  = bk & 7;
  const int b    = xcd >> 2;
  const int slot = (bk >> 3) * 4 + (xcd & 3);
  if (slot >= (NN + TNA - 1) / TNA) return;   // uniform early-out (625 slots/batch)
  const int n0 = slot * TNA;
  const int t  = threadIdx.x;

  const int* eij = ei + b * NN * KK;          // edge_index[0][b] -> j (source)
  const int* eii = ei + (BB + b) * NN * KK;   // edge_index[1][b] -> i (dest)
  const float* sib = si + b * NN;
  const float* sjb = sj + b * NN;

  // Phase A: one edge per thread; softmax over K=16 in-register via
  // 16-lane-group shfl_xor (node nn's 16 edges are lane-contiguous).
  {
    int nn = t >> 4, k = t & 15, gn = n0 + nn;
    int jj = 0, ii = 0;
    if (gn < NN) { jj = eij[gn * KK + k]; ii = eii[gn * KK + k]; }
    float v = sib[ii] + sjb[jj];
    float el = (v > 0.f) ? v : 0.2f * v;   // leaky_relu(0.2)
    float mx = el;
#pragma unroll
    for (int d = 1; d < KK; d <<= 1) mx = fmaxf(mx, __shfl_xor(mx, d));
    float ex = __expf(el - mx);
    float s = ex;
#pragma unroll
    for (int d = 1; d < KK; d <<= 1) s += __shfl_xor(s, d);
    Am[nn][k] = ex / s;
    jd[nn][k] = jj;
  }
  __syncthreads();

  // Phase C: wave = one node row (64 lanes x 1 dword = 256 B); two nodes
  // batched -> 32 independent gathers in flight (all L2-local to this XCD).
  const int cp = t & 63;
  const int nw = t >> 6;
  const uint32* whtb = wht + (size_t)b * NN * (CC / 2);
#pragma unroll
  for (int half = 0; half < 2; ++half) {
    int na = nw + half * 4;        // nodes na and na+8
    uint32 idx[2][KK]; float wk[2][KK];
#pragma unroll
    for (int p = 0; p < 2; ++p) {
      int nn = na + p * 8;
      const uint4*  jp = (const uint4*)&jd[nn][0];   // broadcast b128 reads
      const float4* ap = (const float4*)&Am[nn][0];
#pragma unroll
      for (int g = 0; g < 4; ++g) {
        uint4  jv = jp[g];
        float4 av = ap[g];
        idx[p][4 * g + 0] = jv.x; idx[p][4 * g + 1] = jv.y;
        idx[p][4 * g + 2] = jv.z; idx[p][4 * g + 3] = jv.w;
        wk[p][4 * g + 0] = av.x;  wk[p][4 * g + 1] = av.y;
        wk[p][4 * g + 2] = av.z;  wk[p][4 * g + 3] = av.w;
      }
    }
    uint32 v[2][KK];
#pragma unroll
    for (int p = 0; p < 2; ++p)
#pragma unroll
      for (int k = 0; k < KK; ++k)
        v[p][k] = whtb[idx[p][k] * (uint32)(CC / 2) + (uint32)cp];  // u32 saddr form
#pragma unroll
    for (int p = 0; p < 2; ++p) {
      int nn = na + p * 8;
      float ax = 0.f, ay = 0.f;
#pragma unroll
      for (int k = 0; k < KK; ++k) {
        ax = fmaf(wk[p][k], __uint_as_float(v[p][k] << 16), ax);
        ay = fmaf(wk[p][k], __uint_as_float(v[p][k] & 0xffff0000u), ay);
      }
      outT[2 * cp][nn]     = ax;
      outT[2 * cp + 1][nn] = ay;
    }
  }
  __syncthreads();

  // Phase D: coalesced channel-major store.
  float* outb = out + (size_t)b * CC * NN;
#pragma unroll
  for (int i = 0; i < (CC * TNA) / 256; ++i) {   // 8 iters
    int e = t + i * 256;
    int c = e >> 4, nn = e & 15;
    int gn = n0 + nn;
    if (gn < NN) outb[c * NN + gn] = outT[c][nn];
  }
}

extern "C" void kernel_launch(void* const* d_in, const int* in_sizes, int n_in,
                              void* d_out, int out_size, void* d_ws, size_t ws_size,
                              hipStream_t stream) {
  const float* x  = (const float*)d_in[0];   // [B,C,N,1]
  const int*   ei = (const int*)d_in[1];     // [2,B,N,K]
  const float* W  = (const float*)d_in[2];   // [C,C]
  const float* a  = (const float*)d_in[3];   // [2C]
  float* out = (float*)d_out;                // [B,C,N,1]

  uint32* wht = (uint32*)d_ws;               // [B*N*C/2] bf16 pairs (5.12 MB)
  float*  si  = (float*)(wht + (size_t)BB * NN * (CC / 2));
  float*  sj  = si + BB * NN;

  dim3 g1((NN + TNG - 1) / TNG, BB);   // 313 x 2, 256 threads
  gat_gemm<<<g1, 256, 0, stream>>>(x, W, a, wht, si, sj);
  // 157 groups * 8 XCD-slots = 1256 blocks -> 628 slots/batch (625 used)
  gat_gather<<<dim3(157 * 8), 256, 0, stream>>>(ei, wht, si, sj, out);
}

// Round 4
// 86.781 us; speedup vs baseline: 1.0474x; 1.0011x over previous
//
#include <hip/hip_runtime.h>

// GAT-style graph conv: B=2, C=128, N=10000, K=16, fp32 in/out.
//   k1 (gemm, MFMA bf16): wht[b][n][c] = sum_c' W[c][c']*x[b][c'][n] (bf16 packed)
//               si[b][n] = a[0:C].wh[n], sj[b][n] = a[C:2C].wh[n]  (fp32, from acc)
//   k2 (gather): e = leaky(si[idx_i]+sj[idx_j]); A = softmax_k(e)
//               out[b][c][n] = sum_k A[n,k] * wht[b][idx_j[n,k]][c]
// Gather is XCD-pinned: batch = (blockIdx%8)>>2 so each XCD's L2 (4 MiB) only
// caches its batch's 2.56 MB of wht -> random row-gathers become L2 hits.
// R4: Phase C rebuilt around uint4 row-gathers: each lane loads 16 B, so one
// wave-load covers 4 rows (16 loads/thread vs 64, ~1/4 the addr VALU). Lane
// owns 8 channels of one node; acc order over k unchanged -> bit-identical.

#define BB 2
#define CC 128
#define NN 10000
#define KK 16
#define TNG 32    // nodes per gemm block
#define TNA 16    // nodes per gather block
#define LSTR 136  // xs row stride in ushorts (272 B = 17*16 -> b128-aligned rows)
#define OPAD 132  // outT2 row stride in floats (528 B: 16B-aligned, 2-way banks)

typedef unsigned int uint32;
typedef __attribute__((ext_vector_type(8))) short short8;   // bf16 A/B frag
typedef __attribute__((ext_vector_type(4))) float floatx4;  // f32 C/D frag

__device__ __forceinline__ uint32 bf16pair(float lo, float hi) {
  // round-to-nearest-even bf16, packed (lo low 16, hi high 16)
  uint32 ulo = __float_as_uint(lo);
  uint32 uhi = __float_as_uint(hi);
  ulo += 0x7fffu + ((ulo >> 16) & 1u);
  uhi += 0x7fffu + ((uhi >> 16) & 1u);
  return (ulo >> 16) | (uhi & 0xffff0000u);
}

// ---------------- GEMM via MFMA 16x16x32 bf16, register-resident W frags ----
// Block: 256 thr (4 waves). Wave w: channels w*32..+31 x 32 nodes.
__global__ __launch_bounds__(256) void gat_gemm(
    const float* __restrict__ x,    // [B,C,N]
    const float* __restrict__ W,    // [C,C] row-major W[o][c]
    const float* __restrict__ a,    // [2C]
    uint32* __restrict__ wht,       // [B,N,C/2] bf16 pairs
    float* __restrict__ si,         // [B,N]
    float* __restrict__ sj) {       // [B,N]
  __shared__ unsigned short xs[TNG * LSTR];   // 8704 B, node-major bf16 x tile
  __shared__ float red[2][4][2][16];          // 1 KB si/sj partials

  const int b    = blockIdx.y;
  const int n0   = blockIdx.x * TNG;
  const int t    = threadIdx.x;
  const int w    = t >> 6;       // wave -> channel group w*32
  const int lane = t & 63;
  const int col  = lane & 15;    // MFMA col (node) / A row (channel)
  const int q    = lane >> 4;    // quad -> k offset q*8

  // --- Stage x tile, transpose to node-major bf16 (coalesced 128B row reads) ---
  {
    const float* xb = x + (size_t)b * CC * NN;
    uint32* xd = (uint32*)xs;
#pragma unroll
    for (int i = 0; i < 8; ++i) {
      int e = t + i * 256;
      int n = e & 31, cp = e >> 5;     // cp = channel pair 0..63
      int c = cp * 2, gn = n0 + n;
      float v0 = 0.f, v1 = 0.f;
      if (gn < NN) { v0 = xb[c * NN + gn]; v1 = xb[(c + 1) * NN + gn]; }
      xd[n * 68 + cp] = bf16pair(v0, v1);
    }
  }

  // --- A-fragments straight from global fp32 W -> bf16 registers (no LDS) ---
  short8 af[2][4];
#pragma unroll
  for (int ci = 0; ci < 2; ++ci) {
    const float* wr = W + (w * 32 + ci * 16 + col) * CC;
#pragma unroll
    for (int s = 0; s < 4; ++s) {
      float4 f0 = *(const float4*)(wr + s * 32 + q * 8);
      float4 f1 = *(const float4*)(wr + s * 32 + q * 8 + 4);
      union { uint32 u[4]; short8 v; } cv;
      cv.u[0] = bf16pair(f0.x, f0.y);
      cv.u[1] = bf16pair(f0.z, f0.w);
      cv.u[2] = bf16pair(f1.x, f1.y);
      cv.u[3] = bf16pair(f1.z, f1.w);
      af[ci][s] = cv.v;
    }
  }
  __syncthreads();

  floatx4 acc[2][2];
#pragma unroll
  for (int ci = 0; ci < 2; ++ci)
#pragma unroll
    for (int nj = 0; nj < 2; ++nj) acc[ci][nj] = (floatx4){0.f, 0.f, 0.f, 0.f};

#pragma unroll
  for (int s = 0; s < 4; ++s) {
    short8 bf[2];
#pragma unroll
    for (int nj = 0; nj < 2; ++nj)
      bf[nj] = *(const short8*)(xs + (nj * 16 + col) * LSTR + s * 32 + q * 8);
#pragma unroll
    for (int ci = 0; ci < 2; ++ci)
#pragma unroll
      for (int nj = 0; nj < 2; ++nj)
        acc[ci][nj] = __builtin_amdgcn_mfma_f32_16x16x32_bf16(af[ci][s], bf[nj], acc[ci][nj], 0, 0, 0);
  }

  // --- Epilogue: channel = w*32+ci*16+q*4+r, node = n0+nj*16+col ---
  float ar[2][4], aj4[2][4];
#pragma unroll
  for (int ci = 0; ci < 2; ++ci)
#pragma unroll
    for (int r = 0; r < 4; ++r) {
      int ch = w * 32 + ci * 16 + q * 4 + r;
      ar[ci][r]  = a[ch];
      aj4[ci][r] = a[CC + ch];
    }

#pragma unroll
  for (int nj = 0; nj < 2; ++nj) {
    int node = n0 + nj * 16 + col;
    float psi = 0.f, psj = 0.f;
#pragma unroll
    for (int ci = 0; ci < 2; ++ci) {
#pragma unroll
      for (int r = 0; r < 4; ++r) {
        psi = fmaf(ar[ci][r], acc[ci][nj][r], psi);
        psj = fmaf(aj4[ci][r], acc[ci][nj][r], psj);
      }
      if (node < NN) {
        uint2 pk;
        pk.x = bf16pair(acc[ci][nj][0], acc[ci][nj][1]);
        pk.y = bf16pair(acc[ci][nj][2], acc[ci][nj][3]);
        uint2* dst = (uint2*)(wht + ((size_t)(b * NN + node)) * (CC / 2) + w * 16 + ci * 8 + q * 2);
        *dst = pk;
      }
    }
    psi += __shfl_down(psi, 32);
    psi += __shfl_down(psi, 16);
    psj += __shfl_down(psj, 32);
    psj += __shfl_down(psj, 16);
    if (q == 0) { red[0][w][nj][col] = psi; red[1][w][nj][col] = psj; }
  }
  __syncthreads();

  if (t < TNG) {
    int gn = n0 + t;
    if (gn < NN) {
      int nj = t >> 4, cl = t & 15;
      float s1 = 0.f, s2 = 0.f;
#pragma unroll
      for (int ww = 0; ww < 4; ++ww) { s1 += red[0][ww][nj][cl]; s2 += red[1][ww][nj][cl]; }
      si[b * NN + gn] = s1;
      sj[b * NN + gn] = s2;
    }
  }
}

// ---------------- Gather: XCD-pinned, uint4 row-gathers (4 rows / wave-load) -
__global__ __launch_bounds__(256) void gat_gather(
    const int* __restrict__ ei,      // [2,B,N,K]
    const uint32* __restrict__ wht,  // [B,N,C/2] bf16 pairs
    const float* __restrict__ si,    // [B,N]
    const float* __restrict__ sj,    // [B,N]
    float* __restrict__ out) {       // [B,C,N]
  __shared__ float Am[TNA][KK];        // 1 KB (softmax'd attention weights)
  __shared__ int   jd[TNA][KK];        // 1 KB
  __shared__ float outT2[TNA][OPAD];   // 8.25 KB node-major output tile

  // XCD pinning: xcd = bk%8; XCDs 0-3 -> batch 0, 4-7 -> batch 1.
  const int bk   = blockIdx.x;
  const int xcd  = bk & 7;
  const int b    = xcd >> 2;
  const int slot = (bk >> 3) * 4 + (xcd & 3);
  if (slot >= NN / TNA) return;   // uniform early-out (625 slots/batch, exact)
  const int n0 = slot * TNA;
  const int t  = threadIdx.x;

  const int* eij = ei + b * NN * KK;          // edge_index[0][b] -> j (source)
  const int* eii = ei + (BB + b) * NN * KK;   // edge_index[1][b] -> i (dest)
  const float* sib = si + b * NN;
  const float* sjb = sj + b * NN;

  // Phase A: one edge per thread; softmax over K=16 in-register via
  // 16-lane-group shfl_xor (node nn's 16 edges are lane-contiguous).
  {
    int nn = t >> 4, k = t & 15, gn = n0 + nn;   // gn < NN always (625*16=10000)
    int jj = eij[gn * KK + k];
    int ii = eii[gn * KK + k];
    float v = sib[ii] + sjb[jj];
    float el = (v > 0.f) ? v : 0.2f * v;   // leaky_relu(0.2)
    float mx = el;
#pragma unroll
    for (int d = 1; d < KK; d <<= 1) mx = fmaxf(mx, __shfl_xor(mx, d));
    float ex = __expf(el - mx);
    float s = ex;
#pragma unroll
    for (int d = 1; d < KK; d <<= 1) s += __shfl_xor(s, d);
    Am[nn][k] = ex / s;
    jd[nn][k] = jj;
  }
  __syncthreads();

  // Phase C: lane owns node nn = wave*4 + (lane>>4), channels c16*8..c16*8+7.
  // One uint4 load = 16 B/lane -> a 16-lane quarter covers a full 256 B row,
  // so each wave-load fetches 4 rows. 16 loads/thread (was 64), same bytes.
  const int lane = t & 63;
  const int nw   = t >> 6;
  const int nn   = nw * 4 + (lane >> 4);
  const int c16  = lane & 15;
  const uint32* whtb = wht + (size_t)b * NN * (CC / 2);

  uint32 rows[KK]; float wgt[KK];
  {
    uint4 iv[4]; float4 wv[4];
#pragma unroll
    for (int g = 0; g < 4; ++g) {
      iv[g] = ((const uint4*)&jd[nn][0])[g];    // broadcast within quarter
      wv[g] = ((const float4*)&Am[nn][0])[g];
    }
#pragma unroll
    for (int g = 0; g < 4; ++g) {
      rows[4 * g + 0] = iv[g].x; rows[4 * g + 1] = iv[g].y;
      rows[4 * g + 2] = iv[g].z; rows[4 * g + 3] = iv[g].w;
      wgt[4 * g + 0] = wv[g].x;  wgt[4 * g + 1] = wv[g].y;
      wgt[4 * g + 2] = wv[g].z;  wgt[4 * g + 3] = wv[g].w;
    }
  }

  float acc8[8];
#pragma unroll
  for (int r = 0; r < 8; ++r) acc8[r] = 0.f;

  const uint32 lo4 = (uint32)(c16 * 4);   // dword offset of this lane's quad
#pragma unroll
  for (int half = 0; half < 2; ++half) {  // two batches of 8 loads (VGPR cap)
    uint4 v[8];
#pragma unroll
    for (int k = 0; k < 8; ++k)
      v[k] = *(const uint4*)(whtb + rows[half * 8 + k] * (uint32)(CC / 2) + lo4);
#pragma unroll
    for (int k = 0; k < 8; ++k) {
      float wk = wgt[half * 8 + k];
      uint32 dw[4] = {v[k].x, v[k].y, v[k].z, v[k].w};
#pragma unroll
      for (int d = 0; d < 4; ++d) {
        acc8[2 * d]     = fmaf(wk, __uint_as_float(dw[d] << 16), acc8[2 * d]);
        acc8[2 * d + 1] = fmaf(wk, __uint_as_float(dw[d] & 0xffff0000u), acc8[2 * d + 1]);
      }
    }
  }

  // Store lane's 8 contiguous channels: two b128 LDS stores.
  {
    float* orow = &outT2[nn][c16 * 8];
    *(float4*)(orow)     = (float4){acc8[0], acc8[1], acc8[2], acc8[3]};
    *(float4*)(orow + 4) = (float4){acc8[4], acc8[5], acc8[6], acc8[7]};
  }
  __syncthreads();

  // Phase D: coalesced channel-major store (64 B segments per 16 lanes).
  float* outb = out + (size_t)b * CC * NN;
#pragma unroll
  for (int i = 0; i < (CC * TNA) / 256; ++i) {   // 8 iters
    int e = t + i * 256;
    int c = e >> 4, nd = e & 15;
    outb[c * NN + (n0 + nd)] = outT2[nd][c];
  }
}

extern "C" void kernel_launch(void* const* d_in, const int* in_sizes, int n_in,
                              void* d_out, int out_size, void* d_ws, size_t ws_size,
                              hipStream_t stream) {
  const float* x  = (const float*)d_in[0];   // [B,C,N,1]
  const int*   ei = (const int*)d_in[1];     // [2,B,N,K]
  const float* W  = (const float*)d_in[2];   // [C,C]
  const float* a  = (const float*)d_in[3];   // [2C]
  float* out = (float*)d_out;                // [B,C,N,1]

  uint32* wht = (uint32*)d_ws;               // [B*N*C/2] bf16 pairs (5.12 MB)
  float*  si  = (float*)(wht + (size_t)BB * NN * (CC / 2));
  float*  sj  = si + BB * NN;

  dim3 g1((NN + TNG - 1) / TNG, BB);   // 313 x 2, 256 threads
  gat_gemm<<<g1, 256, 0, stream>>>(x, W, a, wht, si, sj);
  // 157 groups * 8 XCD-slots = 1256 blocks -> 628 slots/batch (625 used)
  gat_gather<<<dim3(157 * 8), 256, 0, stream>>>(ei, wht, si, sj, out);
}